// Round 10
// baseline (524.217 us; speedup 1.0000x reference)
//
#include <hip/hip_runtime.h>
#include <math.h>

// Problem constants: B=4, T=512, S=1024, H=768, V=50257
#define BB 4
#define TT 512
#define SS 1024
#define HH 768
#define VV 50257
#define NW 1571            // ceil(V/32) bitmap words per batch
#define NPROJ 1536         // proj blocks (6144 rows / 4 waves)
#define NROWS (BB * TT)    // 2048 logits rows
#define NV (NROWS * VV)    // 102,926,336 floats (divisible by 4)
#define NG4 (NV / 4)       // 25,731,584 float4 groups
#define MEMB 2048          // memset-role blocks in kernel A
#define MSTRIDE (MEMB * 256)

// ---------------------------------------------------------------------------
// Kernel A (fused prep + global memset):
//   blocks [0, NPROJ)            : projection (one wave per row, 4 rows/blk)
//   blocks [NPROJ, NPROJ+BB)     : per-batch bitmap/prefix -> rank_g
//   blocks [NPROJ+BB, +MEMB)     : ROCCLR-CLONE MEMSET of the whole logits
//                                  region — ONE global grid-stride window,
//                                  16B constant stores, no LDS, no branches.
//                                  This is the only write pattern measured at
//                                  6.1 TB/s (the poison fill); R6 (global
//                                  order + LUT data) and R9 (constant data +
//                                  per-row windows) each lacked one half.
// ---------------------------------------------------------------------------
__global__ __launch_bounds__(256) void prep_kernel(
    const float* __restrict__ src, const float* __restrict__ tgt,
    const float* __restrict__ W, const float* __restrict__ bptr,
    const int* __restrict__ ids,
    float* __restrict__ src_proj, float* __restrict__ tgt_proj,
    unsigned short* __restrict__ rank_g, float* __restrict__ out)
{
    __shared__ unsigned bm[NW];
    __shared__ unsigned pre[NW];
    __shared__ unsigned scan[256];
    const int tid = threadIdx.x;

    if (blockIdx.x >= NPROJ + BB) {
        // ---- memset role: pure constant fill, global marching window ----
        float4* zp = (float4*)(out + NROWS);
        const float4 z4 = make_float4(0.f, 0.f, 0.f, 0.f);
        for (int g = (blockIdx.x - (NPROJ + BB)) * 256 + tid; g < NG4;
             g += MSTRIDE)
            zp[g] = z4;
        return;
    }

    if (blockIdx.x < NPROJ) {
        // ---- projection role: one wave per row, 4 rows/block ----
        const int wave = tid >> 6;
        const int lane = tid & 63;
        const int row  = blockIdx.x * 4 + wave;   // 0 .. 6143

        const float* vec;
        const float* w;
        if (row < BB * SS) { vec = src + (size_t)row * HH;            w = W; }
        else               { vec = tgt + (size_t)(row - BB*SS) * HH;  w = W + HH; }
        const float4* v4 = (const float4*)vec;
        const float4* w4 = (const float4*)w;

        float acc = 0.f;
#pragma unroll
        for (int k = 0; k < 3; ++k) {
            float4 a = v4[k * 64 + lane];
            float4 b = w4[k * 64 + lane];
            acc += a.x * b.x + a.y * b.y + a.z * b.z + a.w * b.w;
        }
#pragma unroll
        for (int off = 32; off > 0; off >>= 1) acc += __shfl_down(acc, off);
        if (lane == 0) {
            if (row < BB * SS) src_proj[row] = acc;
            else               tgt_proj[row - BB * SS] = acc + bptr[0];
        }
        return;
    }

    // ---- setup role: one block per batch ----
    const int b = blockIdx.x - NPROJ;

    for (int i = tid; i < NW; i += 256) bm[i] = 0u;
    __syncthreads();
    const int* idb = ids + b * SS;
    for (int s = tid; s < SS; s += 256) {
        const int v = idb[s];
        atomicOr(&bm[v >> 5], 1u << (v & 31));
    }
    __syncthreads();

    unsigned cnt[7];
    unsigned local = 0;
    const int w0 = tid * 7;                 // 256*7 = 1792 >= 1571
#pragma unroll
    for (int k = 0; k < 7; ++k) {
        const int w = w0 + k;
        cnt[k] = local;
        local += (w < NW) ? (unsigned)__popc(bm[w]) : 0u;
    }
    scan[tid] = local;
    __syncthreads();
    for (int off = 1; off < 256; off <<= 1) {
        const unsigned mine = scan[tid];
        const unsigned add  = (tid >= off) ? scan[tid - off] : 0u;
        __syncthreads();
        scan[tid] = mine + add;
        __syncthreads();
    }
    const unsigned excl = (tid > 0) ? scan[tid - 1] : 0u;
#pragma unroll
    for (int k = 0; k < 7; ++k) {
        const int w = w0 + k;
        if (w < NW) pre[w] = excl + cnt[k];
    }
    __syncthreads();
    for (int s = tid; s < SS; s += 256) {
        const int v = idb[s];
        const unsigned w = (unsigned)v >> 5, bit = (unsigned)v & 31u;
        const unsigned r = pre[w] + (unsigned)__popc(bm[w] & ((1u << bit) - 1u));
        rank_g[b * SS + s] = (unsigned short)r;
    }
}

// ---------------------------------------------------------------------------
// Kernel B (sparse): one block per (b,t) row. The logits row is already
// zeroed by kernel A's memset role (stream-ordered). This kernel only:
//   pass 0: vals[rank[s]] += attn[row,s] (LDS atomics) + p_gen dot.
//   pass 1: scatter-overwrite the <=1024 dirty positions from LDS vals
//           (verified correct in R9: duplicates write identical values).
// ---------------------------------------------------------------------------
__global__ __launch_bounds__(256) void row_kernel(
    const float* __restrict__ attn,
    const float* __restrict__ src_proj,
    const float* __restrict__ tgt_proj,
    const unsigned short* __restrict__ rank_g,
    const int* __restrict__ ids,
    float* __restrict__ out)
{
    __shared__ float vals[SS];
    __shared__ float wsum[4];

    const int row = blockIdx.x;     // 0 .. B*T-1
    const int b   = row >> 9;       // T = 512
    const int tid = threadIdx.x;

    ((float4*)vals)[tid] = make_float4(0.f, 0.f, 0.f, 0.f);
    __syncthreads();

    // ---- pass 0: vals accumulate + p_gen dot (1024 = 4*256, vectorized) ----
    const float4  a = ((const float4*)(attn + (size_t)row * SS))[tid];
    const float4  p = ((const float4*)(src_proj + b * SS))[tid];
    const ushort4 r = ((const ushort4*)(rank_g + b * SS))[tid];
    atomicAdd(&vals[r.x], a.x);
    atomicAdd(&vals[r.y], a.y);
    atomicAdd(&vals[r.z], a.z);
    atomicAdd(&vals[r.w], a.w);
    float acc = a.x * p.x + a.y * p.y + a.z * p.z + a.w * p.w;
#pragma unroll
    for (int off = 32; off > 0; off >>= 1) acc += __shfl_down(acc, off);
    if ((tid & 63) == 0) wsum[tid >> 6] = acc;
    __syncthreads();   // vals final + wsum visible

    if (tid == 0) {
        const float x = wsum[0] + wsum[1] + wsum[2] + wsum[3] + tgt_proj[row];
        out[row] = 1.f / (1.f + expf(-x));
    }

    // ---- pass 1: scatter-overwrite dirty positions (values from LDS) ----
    float* lp = out + NROWS + (size_t)row * VV;
    const int*            idb = ids    + b * SS;
    const unsigned short* rb  = rank_g + b * SS;
    for (int s = tid; s < SS; s += 256)
        lp[idb[s]] = vals[rb[s]];           // duplicates: same rank -> same value
}

extern "C" void kernel_launch(void* const* d_in, const int* in_sizes, int n_in,
                              void* d_out, int out_size, void* d_ws, size_t ws_size,
                              hipStream_t stream) {
    const int*   ids  = (const int*)d_in[0];    // [B,S]
    const float* attn = (const float*)d_in[1];  // [B,T,S]
    const float* src  = (const float*)d_in[2];  // [B,S,H]
    const float* tgt  = (const float*)d_in[3];  // [B,T,H]
    const float* W    = (const float*)d_in[4];  // [2H,1]
    const float* bp   = (const float*)d_in[5];  // [1]

    float* out = (float*)d_out;                 // [B*T (p_gen) | B*T*V]

    // ws layout (all 16B-aligned)
    float*          src_proj = (float*)d_ws;                          // 4096 f
    float*          tgt_proj = src_proj + BB * SS;                    // 2048 f
    unsigned short* rank_g   = (unsigned short*)(tgt_proj + BB * TT); // B*S u16

    prep_kernel<<<NPROJ + BB + MEMB, 256, 0, stream>>>(
        src, tgt, W, bp, ids, src_proj, tgt_proj, rank_g, out);
    row_kernel<<<NROWS, 256, 0, stream>>>(
        attn, src_proj, tgt_proj, rank_g, ids, out);
}

// Round 11
// 519.684 us; speedup vs baseline: 1.0087x; 1.0087x over previous
//
#include <hip/hip_runtime.h>
#include <math.h>

// Problem constants: B=4, T=512, S=1024, H=768, V=50257
#define BB 4
#define TT 512
#define SS 1024
#define HH 768
#define VV 50257
#define NW 1571            // ceil(V/32) bitmap words per batch
#define NPROJ 1536         // proj blocks (6144 rows / 4 waves)
#define NROWS (BB * TT)    // 2048 logits rows
#define NV ((size_t)NROWS * VV)   // logits floats

// ---------------------------------------------------------------------------
// Kernel P: blocks [0,1536) projections; blocks [1536,1540) per-batch setup.
// Setup now also emits the SORTED UNIQUE id list: uids[rank] = id (rank is
// the position in sorted-unique order, so vals[j] pairs with uids[j]), and
// nuniq (= scan total). Row kernel scatters in ascending-address order.
// ---------------------------------------------------------------------------
__global__ __launch_bounds__(256) void prep_kernel(
    const float* __restrict__ src, const float* __restrict__ tgt,
    const float* __restrict__ W, const float* __restrict__ bptr,
    const int* __restrict__ ids,
    float* __restrict__ src_proj, float* __restrict__ tgt_proj,
    unsigned short* __restrict__ rank_g, unsigned short* __restrict__ uids_g,
    int* __restrict__ nuniq_g)
{
    __shared__ unsigned bm[NW];
    __shared__ unsigned pre[NW];
    __shared__ unsigned scan[256];
    const int tid = threadIdx.x;

    if (blockIdx.x < NPROJ) {
        // ---- projection role: one wave per row, 4 rows/block ----
        const int wave = tid >> 6;
        const int lane = tid & 63;
        const int row  = blockIdx.x * 4 + wave;   // 0 .. 6143

        const float* vec;
        const float* w;
        if (row < BB * SS) { vec = src + (size_t)row * HH;            w = W; }
        else               { vec = tgt + (size_t)(row - BB*SS) * HH;  w = W + HH; }
        const float4* v4 = (const float4*)vec;
        const float4* w4 = (const float4*)w;

        float acc = 0.f;
#pragma unroll
        for (int k = 0; k < 3; ++k) {
            float4 a = v4[k * 64 + lane];
            float4 b = w4[k * 64 + lane];
            acc += a.x * b.x + a.y * b.y + a.z * b.z + a.w * b.w;
        }
#pragma unroll
        for (int off = 32; off > 0; off >>= 1) acc += __shfl_down(acc, off);
        if (lane == 0) {
            if (row < BB * SS) src_proj[row] = acc;
            else               tgt_proj[row - BB * SS] = acc + bptr[0];
        }
        return;
    }

    // ---- setup role: one block per batch ----
    const int b = blockIdx.x - NPROJ;

    for (int i = tid; i < NW; i += 256) bm[i] = 0u;
    __syncthreads();
    const int* idb = ids + b * SS;
    for (int s = tid; s < SS; s += 256) {
        const int v = idb[s];
        atomicOr(&bm[v >> 5], 1u << (v & 31));
    }
    __syncthreads();

    unsigned cnt[7];
    unsigned local = 0;
    const int w0 = tid * 7;                 // 256*7 = 1792 >= 1571
#pragma unroll
    for (int k = 0; k < 7; ++k) {
        const int w = w0 + k;
        cnt[k] = local;
        local += (w < NW) ? (unsigned)__popc(bm[w]) : 0u;
    }
    scan[tid] = local;
    __syncthreads();
    for (int off = 1; off < 256; off <<= 1) {
        const unsigned mine = scan[tid];
        const unsigned add  = (tid >= off) ? scan[tid - off] : 0u;
        __syncthreads();
        scan[tid] = mine + add;
        __syncthreads();
    }
    const unsigned excl = (tid > 0) ? scan[tid - 1] : 0u;
#pragma unroll
    for (int k = 0; k < 7; ++k) {
        const int w = w0 + k;
        if (w < NW) pre[w] = excl + cnt[k];
    }
    if (tid == 255) nuniq_g[b] = (int)scan[255];   // total unique count
    __syncthreads();
    for (int s = tid; s < SS; s += 256) {
        const int v = idb[s];
        const unsigned w = (unsigned)v >> 5, bit = (unsigned)v & 31u;
        const unsigned r = pre[w] + (unsigned)__popc(bm[w] & ((1u << bit) - 1u));
        rank_g[b * SS + s] = (unsigned short)r;
        uids_g[b * SS + r] = (unsigned short)v;    // sorted-unique id list
    }
}

// ---------------------------------------------------------------------------
// Kernel B (sparse): one block per (b,t) row. Logits already zeroed by the
// runtime's fillBufferAligned (hipMemsetAsync — the only store path measured
// at 6.1 TB/s; R10 proved an in-kernel clone can't match it).
//   pass 0: vals[rank[s]] += attn[row,s] (LDS atomics) + p_gen dot.
//   pass 1: sorted-order scatter of nuniq (<=1024) dwords: lp[uids[j]] =
//           vals[j] — ascending addresses, j == rank pairing.
// ---------------------------------------------------------------------------
__global__ __launch_bounds__(256) void row_kernel(
    const float* __restrict__ attn,
    const float* __restrict__ src_proj,
    const float* __restrict__ tgt_proj,
    const unsigned short* __restrict__ rank_g,
    const unsigned short* __restrict__ uids_g,
    const int* __restrict__ nuniq_g,
    float* __restrict__ out)
{
    __shared__ float vals[SS];
    __shared__ float wsum[4];

    const int row = blockIdx.x;     // 0 .. B*T-1
    const int b   = row >> 9;       // T = 512
    const int tid = threadIdx.x;

    ((float4*)vals)[tid] = make_float4(0.f, 0.f, 0.f, 0.f);
    __syncthreads();

    // ---- pass 0: vals accumulate + p_gen dot (1024 = 4*256, vectorized) ----
    const float4  a = ((const float4*)(attn + (size_t)row * SS))[tid];
    const float4  p = ((const float4*)(src_proj + b * SS))[tid];
    const ushort4 r = ((const ushort4*)(rank_g + b * SS))[tid];
    atomicAdd(&vals[r.x], a.x);
    atomicAdd(&vals[r.y], a.y);
    atomicAdd(&vals[r.z], a.z);
    atomicAdd(&vals[r.w], a.w);
    float acc = a.x * p.x + a.y * p.y + a.z * p.z + a.w * p.w;
#pragma unroll
    for (int off = 32; off > 0; off >>= 1) acc += __shfl_down(acc, off);
    if ((tid & 63) == 0) wsum[tid >> 6] = acc;
    __syncthreads();   // vals final + wsum visible

    if (tid == 0) {
        const float x = wsum[0] + wsum[1] + wsum[2] + wsum[3] + tgt_proj[row];
        out[row] = 1.f / (1.f + expf(-x));
    }

    // ---- pass 1: sorted-order sparse scatter (j == rank pairing) ----
    float* lp = out + NROWS + (size_t)row * VV;
    const int nuniq = nuniq_g[b];
    const unsigned short* ub = uids_g + b * SS;
    for (int j = tid; j < nuniq; j += 256)
        lp[ub[j]] = vals[j];
}

extern "C" void kernel_launch(void* const* d_in, const int* in_sizes, int n_in,
                              void* d_out, int out_size, void* d_ws, size_t ws_size,
                              hipStream_t stream) {
    const int*   ids  = (const int*)d_in[0];    // [B,S]
    const float* attn = (const float*)d_in[1];  // [B,T,S]
    const float* src  = (const float*)d_in[2];  // [B,S,H]
    const float* tgt  = (const float*)d_in[3];  // [B,T,H]
    const float* W    = (const float*)d_in[4];  // [2H,1]
    const float* bp   = (const float*)d_in[5];  // [1]

    float* out = (float*)d_out;                 // [B*T (p_gen) | B*T*V]

    // ws layout (all 16B-aligned)
    float*          src_proj = (float*)d_ws;                          // 4096 f
    float*          tgt_proj = src_proj + BB * SS;                    // 2048 f
    unsigned short* rank_g   = (unsigned short*)(tgt_proj + BB * TT); // B*S u16
    unsigned short* uids_g   = rank_g + BB * SS;                      // B*S u16
    int*            nuniq_g  = (int*)(uids_g + BB * SS);              // 4 i32

    // Zero the logits region via the runtime's own fill kernel (the one
    // store path measured at 6.1 TB/s on this buffer). Graph-capture-safe
    // (memset node), stream-ordered before row_kernel's scatter.
    hipMemsetAsync(out + NROWS, 0, NV * sizeof(float), stream);

    prep_kernel<<<NPROJ + BB, 256, 0, stream>>>(
        src, tgt, W, bp, ids, src_proj, tgt_proj, rank_g, uids_g, nuniq_g);
    row_kernel<<<NROWS, 256, 0, stream>>>(
        attn, src_proj, tgt_proj, rank_g, uids_g, nuniq_g, out);
}

// Round 12
// 513.622 us; speedup vs baseline: 1.0206x; 1.0118x over previous
//
#include <hip/hip_runtime.h>
#include <math.h>

// Problem constants: B=4, T=512, S=1024, H=768, V=50257
#define BB 4
#define TT 512
#define SS 1024
#define HH 768
#define VV 50257
#define NW 1571            // ceil(V/32) bitmap words per batch
#define NWP 1600           // uint2 stride per batch for bmpre_g (>= NW+1)
#define NPROJ 1536         // proj blocks (6144 rows / 4 waves)
#define NROWS (BB * TT)    // 2048 logits rows
#define NV ((size_t)NROWS * VV)   // logits floats

// ---------------------------------------------------------------------------
// Kernel P: blocks [0,1536) projections; blocks [1536,1540) per-batch setup.
// Emits: bm|pre interleaved uint2 (+zero sentinel at NW), rank_g (for the
// accumulate), sorted-unique id list uids_g[rank]=id, and nuniq.
// ---------------------------------------------------------------------------
__global__ __launch_bounds__(256) void prep_kernel(
    const float* __restrict__ src, const float* __restrict__ tgt,
    const float* __restrict__ W, const float* __restrict__ bptr,
    const int* __restrict__ ids,
    float* __restrict__ src_proj, float* __restrict__ tgt_proj,
    uint2* __restrict__ bmpre_g, unsigned short* __restrict__ rank_g,
    unsigned short* __restrict__ uids_g, int* __restrict__ nuniq_g)
{
    __shared__ unsigned bm[NW];
    __shared__ unsigned pre[NW];
    __shared__ unsigned scan[256];
    const int tid = threadIdx.x;

    if (blockIdx.x < NPROJ) {
        // ---- projection role: one wave per row, 4 rows/block ----
        const int wave = tid >> 6;
        const int lane = tid & 63;
        const int row  = blockIdx.x * 4 + wave;   // 0 .. 6143

        const float* vec;
        const float* w;
        if (row < BB * SS) { vec = src + (size_t)row * HH;            w = W; }
        else               { vec = tgt + (size_t)(row - BB*SS) * HH;  w = W + HH; }
        const float4* v4 = (const float4*)vec;
        const float4* w4 = (const float4*)w;

        float acc = 0.f;
#pragma unroll
        for (int k = 0; k < 3; ++k) {
            float4 a = v4[k * 64 + lane];
            float4 b = w4[k * 64 + lane];
            acc += a.x * b.x + a.y * b.y + a.z * b.z + a.w * b.w;
        }
#pragma unroll
        for (int off = 32; off > 0; off >>= 1) acc += __shfl_down(acc, off);
        if (lane == 0) {
            if (row < BB * SS) src_proj[row] = acc;
            else               tgt_proj[row - BB * SS] = acc + bptr[0];
        }
        return;
    }

    // ---- setup role: one block per batch ----
    const int b = blockIdx.x - NPROJ;

    for (int i = tid; i < NW; i += 256) bm[i] = 0u;
    __syncthreads();
    const int* idb = ids + b * SS;
    for (int s = tid; s < SS; s += 256) {
        const int v = idb[s];
        atomicOr(&bm[v >> 5], 1u << (v & 31));
    }
    __syncthreads();

    unsigned cnt[7];
    unsigned local = 0;
    const int w0 = tid * 7;                 // 256*7 = 1792 >= 1571
#pragma unroll
    for (int k = 0; k < 7; ++k) {
        const int w = w0 + k;
        cnt[k] = local;
        local += (w < NW) ? (unsigned)__popc(bm[w]) : 0u;
    }
    scan[tid] = local;
    __syncthreads();
    for (int off = 1; off < 256; off <<= 1) {
        const unsigned mine = scan[tid];
        const unsigned add  = (tid >= off) ? scan[tid - off] : 0u;
        __syncthreads();
        scan[tid] = mine + add;
        __syncthreads();
    }
    const unsigned excl = (tid > 0) ? scan[tid - 1] : 0u;
#pragma unroll
    for (int k = 0; k < 7; ++k) {
        const int w = w0 + k;
        if (w < NW) {
            const unsigned p = excl + cnt[k];
            pre[w] = p;
            bmpre_g[b * NWP + w] = make_uint2(bm[w], p);
        }
    }
    if (tid == 0)   bmpre_g[b * NWP + NW] = make_uint2(0u, 0u);  // sentinel
    if (tid == 255) nuniq_g[b] = (int)scan[255];                 // unique count
    __syncthreads();
    for (int s = tid; s < SS; s += 256) {
        const int v = idb[s];
        const unsigned w = (unsigned)v >> 5, bit = (unsigned)v & 31u;
        const unsigned r = pre[w] + (unsigned)__popc(bm[w] & ((1u << bit) - 1u));
        rank_g[b * SS + s] = (unsigned short)r;
        uids_g[b * SS + r] = (unsigned short)v;    // sorted-unique id list
    }
}

// branch-free lut: value if id-bit set, else 0. vals padded so the
// speculative read (index <= nuniq <= 1024) stays in-bounds.
__device__ __forceinline__ float lutv(int v, const uint2* __restrict__ bmpre,
                                      const float* __restrict__ vals)
{
    const uint2 bp = bmpre[v >> 5];
    const unsigned bt = (unsigned)v & 31u;
    const float  x = vals[bp.y + (unsigned)__popc(bp.x & ((1u << bt) - 1u))];
    return ((bp.x >> bt) & 1u) ? x : 0.f;
}

// ---------------------------------------------------------------------------
// Kernel B: one block per (b,t) row. Logits pre-zeroed by hipMemsetAsync
// (runtime fillBufferAligned).
//   pass 0: vals[rank[s]] += attn[row,s] (LDS atomics) + p_gen dot.
//   pass 1: FULL-64B-LINE sparse writes. Walk the sorted unique id list;
//           the thread holding the first id of each physical 64B line writes
//           that whole line (4 aligned float4 stores, lut values + zeros).
//           Full-line stores need no L2/HBM read-for-ownership — removes
//           R11's ~200 MB hidden RMW traffic and its latency stalls.
//           Edge lines (row start/end) take a scalar masked path.
// ---------------------------------------------------------------------------
__global__ __launch_bounds__(256) void row_kernel(
    const float* __restrict__ attn,
    const float* __restrict__ src_proj,
    const float* __restrict__ tgt_proj,
    const uint2* __restrict__ bmpre_g,
    const unsigned short* __restrict__ rank_g,
    const unsigned short* __restrict__ uids_g,
    const int* __restrict__ nuniq_g,
    float* __restrict__ out)
{
    __shared__ uint2 bmpre[NW + 1];
    __shared__ float vals[SS + 4];          // +4 pad for speculative lut read
    __shared__ float wsum[4];

    const int row = blockIdx.x;     // 0 .. B*T-1
    const int b   = row >> 9;       // T = 512
    const int tid = threadIdx.x;

    for (int i = tid; i < NW + 1; i += 256) bmpre[i] = bmpre_g[b * NWP + i];
    ((float4*)vals)[tid] = make_float4(0.f, 0.f, 0.f, 0.f);
    if (tid < 4) vals[SS + tid] = 0.f;
    __syncthreads();

    // ---- pass 0: vals accumulate + p_gen dot (1024 = 4*256, vectorized) ----
    const float4  a = ((const float4*)(attn + (size_t)row * SS))[tid];
    const float4  p = ((const float4*)(src_proj + b * SS))[tid];
    const ushort4 r = ((const ushort4*)(rank_g + b * SS))[tid];
    atomicAdd(&vals[r.x], a.x);
    atomicAdd(&vals[r.y], a.y);
    atomicAdd(&vals[r.z], a.z);
    atomicAdd(&vals[r.w], a.w);
    float acc = a.x * p.x + a.y * p.y + a.z * p.z + a.w * p.w;
#pragma unroll
    for (int off = 32; off > 0; off >>= 1) acc += __shfl_down(acc, off);
    if ((tid & 63) == 0) wsum[tid >> 6] = acc;
    __syncthreads();   // vals final + wsum visible

    if (tid == 0) {
        const float x = wsum[0] + wsum[1] + wsum[2] + wsum[3] + tgt_proj[row];
        out[row] = 1.f / (1.f + expf(-x));
    }

    // ---- pass 1: full-line sparse writes from the sorted unique list ----
    float* lp = out + NROWS + (size_t)row * VV;
    const int phi = (int)(((uintptr_t)lp >> 2) & 15u); // base offset in line
    const int nuniq = nuniq_g[b];
    const unsigned short* ub = uids_g + b * SS;

    for (int j = tid; j < nuniq; j += 256) {
        const int id = ub[j];
        const int k  = (id + phi) >> 4;                // physical line index
        if (j > 0 && (((int)ub[j - 1] + phi) >> 4) == k) continue; // not start
        const int v0 = (k << 4) - phi;                 // first float of line
        if (v0 >= 0 && v0 + 16 <= VV) {
#pragma unroll
            for (int q = 0; q < 4; ++q) {
                const int vq = v0 + (q << 2);
                float4 o;
                o.x = lutv(vq,     bmpre, vals);
                o.y = lutv(vq + 1, bmpre, vals);
                o.z = lutv(vq + 2, bmpre, vals);
                o.w = lutv(vq + 3, bmpre, vals);
                *(float4*)(lp + vq) = o;               // 64B-line aligned
            }
        } else {                                       // edge line, scalar
            const int lo = (v0 < 0) ? 0 : v0;
            const int hi = (v0 + 16 > VV) ? VV : v0 + 16;
            for (int q = lo; q < hi; ++q) lp[q] = lutv(q, bmpre, vals);
        }
    }
}

extern "C" void kernel_launch(void* const* d_in, const int* in_sizes, int n_in,
                              void* d_out, int out_size, void* d_ws, size_t ws_size,
                              hipStream_t stream) {
    const int*   ids  = (const int*)d_in[0];    // [B,S]
    const float* attn = (const float*)d_in[1];  // [B,T,S]
    const float* src  = (const float*)d_in[2];  // [B,S,H]
    const float* tgt  = (const float*)d_in[3];  // [B,T,H]
    const float* W    = (const float*)d_in[4];  // [2H,1]
    const float* bp   = (const float*)d_in[5];  // [1]

    float* out = (float*)d_out;                 // [B*T (p_gen) | B*T*V]

    // ws layout (all 16B-aligned)
    float*          src_proj = (float*)d_ws;                          // 4096 f
    float*          tgt_proj = src_proj + BB * SS;                    // 2048 f
    uint2*          bmpre_g  = (uint2*)(tgt_proj + BB * TT);          // B*NWP uint2
    unsigned short* rank_g   = (unsigned short*)(bmpre_g + BB * NWP); // B*S u16
    unsigned short* uids_g   = rank_g + BB * SS;                      // B*S u16
    int*            nuniq_g  = (int*)(uids_g + BB * SS);              // 4 i32

    // Bulk zero via the runtime's fill kernel (stream-ordered, capture-safe).
    hipMemsetAsync(out + NROWS, 0, NV * sizeof(float), stream);

    prep_kernel<<<NPROJ + BB, 256, 0, stream>>>(
        src, tgt, W, bp, ids, src_proj, tgt_proj, bmpre_g, rank_g,
        uids_g, nuniq_g);
    row_kernel<<<NROWS, 256, 0, stream>>>(
        attn, src_proj, tgt_proj, bmpre_g, rank_g, uids_g, nuniq_g, out);
}

// Round 13
// 462.452 us; speedup vs baseline: 1.1336x; 1.1107x over previous
//
#include <hip/hip_runtime.h>
#include <math.h>

// Problem constants: B=4, T=512, S=1024, H=768, V=50257
#define BB 4
#define TT 512
#define SS 1024
#define HH 768
#define VV 50257
#define NW 1571            // ceil(V/32) bitmap words per batch
#define NWP 1600           // uint2 stride per batch for bmpre_g (>= NW+1)
#define NPROJ 1536         // proj blocks (6144 rows / 4 waves)
#define KPB 257            // row-blocks per batch: 255 pairs + 2 singles

// ---------------------------------------------------------------------------
// FINAL KERNEL — empirical optimum of the session (R5: 462.4 us, absmax 0).
// Eight organizations of the mandatory 412 MB logits write all landed at
// 462-479 us normalized (LUT sweeps x3, global-marching sweep, in-kernel
// memset+scatter x2, runtime-fill memset + scatter x2). The add-on over the
// harness poison (~268 us) is pinned at ~195 us regardless of instruction
// count, LDS ops, occupancy, topology, burst order, marching order, store
// pipelining, RMW elimination, or write issuer — a platform property of
// distributing non-fill stores from kernel code in this harness window.
// ---------------------------------------------------------------------------
__global__ __launch_bounds__(256) void prep_kernel(
    const float* __restrict__ src, const float* __restrict__ tgt,
    const float* __restrict__ W, const float* __restrict__ bptr,
    const int* __restrict__ ids,
    float* __restrict__ src_proj, float* __restrict__ tgt_proj,
    uint2* __restrict__ bmpre_g, unsigned short* __restrict__ rank_g)
{
    __shared__ unsigned bm[NW];
    __shared__ unsigned pre[NW];
    __shared__ unsigned scan[256];
    const int tid = threadIdx.x;

    if (blockIdx.x < NPROJ) {
        // ---- projection role: one wave per row, 4 rows/block ----
        const int wave = tid >> 6;
        const int lane = tid & 63;
        const int row  = blockIdx.x * 4 + wave;   // 0 .. 6143

        const float* vec;
        const float* w;
        if (row < BB * SS) { vec = src + (size_t)row * HH;            w = W; }
        else               { vec = tgt + (size_t)(row - BB*SS) * HH;  w = W + HH; }
        const float4* v4 = (const float4*)vec;
        const float4* w4 = (const float4*)w;

        float acc = 0.f;
#pragma unroll
        for (int k = 0; k < 3; ++k) {
            float4 a = v4[k * 64 + lane];
            float4 b = w4[k * 64 + lane];
            acc += a.x * b.x + a.y * b.y + a.z * b.z + a.w * b.w;
        }
#pragma unroll
        for (int off = 32; off > 0; off >>= 1) acc += __shfl_down(acc, off);
        if (lane == 0) {
            if (row < BB * SS) src_proj[row] = acc;
            else               tgt_proj[row - BB * SS] = acc + bptr[0];
        }
        return;
    }

    // ---- setup role: one block per batch ----
    const int b = blockIdx.x - NPROJ;

    for (int i = tid; i < NW; i += 256) bm[i] = 0u;
    __syncthreads();
    const int* idb = ids + b * SS;
    for (int s = tid; s < SS; s += 256) {
        const int v = idb[s];
        atomicOr(&bm[v >> 5], 1u << (v & 31));
    }
    __syncthreads();

    unsigned cnt[7];
    unsigned local = 0;
    const int w0 = tid * 7;                 // 256*7 = 1792 >= 1571
#pragma unroll
    for (int k = 0; k < 7; ++k) {
        const int w = w0 + k;
        cnt[k] = local;
        local += (w < NW) ? (unsigned)__popc(bm[w]) : 0u;
    }
    scan[tid] = local;
    __syncthreads();
    for (int off = 1; off < 256; off <<= 1) {
        const unsigned mine = scan[tid];
        const unsigned add  = (tid >= off) ? scan[tid - off] : 0u;
        __syncthreads();
        scan[tid] = mine + add;
        __syncthreads();
    }
    const unsigned excl = (tid > 0) ? scan[tid - 1] : 0u;
#pragma unroll
    for (int k = 0; k < 7; ++k) {
        const int w = w0 + k;
        if (w < NW) {
            const unsigned p = excl + cnt[k];
            pre[w] = p;
            bmpre_g[b * NWP + w] = make_uint2(bm[w], p);
        }
    }
    if (tid == 0) bmpre_g[b * NWP + NW] = make_uint2(0u, 0u);  // sentinel
    __syncthreads();
    for (int s = tid; s < SS; s += 256) {
        const int v = idb[s];
        const unsigned w = (unsigned)v >> 5, bit = (unsigned)v & 31u;
        const unsigned r = pre[w] + (unsigned)__popc(bm[w] & ((1u << bit) - 1u));
        rank_g[b * SS + s] = (unsigned short)r;
    }
}

// lut for one vocab index u: returns (row_a_val, row_b_val) or zeros.
__device__ __forceinline__ float2 lut2(int u, const uint2* __restrict__ bmpre,
                                       const float2* __restrict__ vals2)
{
    const uint2 bp = bmpre[u >> 5];
    const unsigned bt = (unsigned)u & 31u;
    if ((bp.x >> bt) & 1u)
        return vals2[bp.y + (unsigned)__popc(bp.x & ((1u << bt) - 1u))];
    return make_float2(0.f, 0.f);
}

// one element of the shared 5-wide window; t = s + j, word = w (+1 if t>=32)
#define ELEM(J, DST)                                                        \
    if (m5 & (1u << (J))) {                                                 \
        const unsigned t  = (unsigned)s + (J);                              \
        const unsigned bw = (t >= 32u) ? bp1.x : bp0.x;                     \
        const unsigned pw = (t >= 32u) ? bp1.y : bp0.y;                     \
        const unsigned bt = t & 31u;                                        \
        DST = vals2[pw + (unsigned)__popc(bw & ((1u << bt) - 1u))];         \
    }

// pair body: writes group IVAR of row_a (la) and row_b (lb, shifted -1)
#define PAIR_BODY(IVAR)                                                     \
    {                                                                       \
        const int v = h + ((IVAR) << 2);                                    \
        const int s = (v - 1) & 31;                                         \
        const int w = (v - 1) >> 5;                                         \
        const uint2 bp0 = bmpre[w];                                         \
        const uint2 bp1 = bmpre[w + 1];                                     \
        unsigned m5 = bp0.x >> s;                                           \
        if (s >= 28) m5 |= (bp1.x << (32 - s));                             \
        m5 &= 31u;                                                          \
        float2 e0 = make_float2(0.f,0.f), e1 = e0, e2 = e0, e3 = e0, e4 = e0;\
        if (m5) { ELEM(0, e0) ELEM(1, e1) ELEM(2, e2) ELEM(3, e3) ELEM(4, e4) } \
        *(float4*)(la + v)     = make_float4(e1.x, e2.x, e3.x, e4.x);       \
        *(float4*)(lb + v - 1) = make_float4(e0.y, e1.y, e2.y, e3.y);       \
    }

// single-row body
#define SINGLE_BODY(IVAR)                                                   \
    {                                                                       \
        const int v = h + ((IVAR) << 2);                                    \
        const int s = v & 31;                                               \
        const int w = v >> 5;                                               \
        const uint2 bp0 = bmpre[w];                                         \
        const uint2 bp1 = bmpre[w + 1];                                     \
        unsigned m5 = bp0.x >> s;                                           \
        if (s >= 29) m5 |= (bp1.x << (32 - s));                             \
        m5 &= 15u;                                                          \
        float2 e0 = make_float2(0.f,0.f), e1 = e0, e2 = e0, e3 = e0;        \
        if (m5) { ELEM(0, e0) ELEM(1, e1) ELEM(2, e2) ELEM(3, e3) }         \
        *(float4*)(la + v) = make_float4(e0.x, e1.x, e2.x, e3.x);           \
    }

// ---------------------------------------------------------------------------
// Kernel B: one block per ROW PAIR (2k+1, 2k+2) of a batch (255 pairs) plus
// two single-row blocks (rows 0, 511). Pair trick: row base mod 4 floats ==
// row mod 4, so head_b == head_a - 1 and both rows' aligned float4 groups
// come from ONE shared 5-element vocab window [v-1, v+3]. Sweep order: each
// wave writes a 4KB contiguous window in 4 back-to-back coalesced 1KB store
// instructions (16KB contiguous per block per outer iteration).
// ---------------------------------------------------------------------------
__global__ __launch_bounds__(256) void row_kernel(
    const float* __restrict__ attn,
    const float* __restrict__ src_proj,
    const float* __restrict__ tgt_proj,
    const uint2* __restrict__ bmpre_g,
    const unsigned short* __restrict__ rank_g,
    float* __restrict__ out)
{
    __shared__ uint2  bmpre[NW + 1];
    __shared__ float2 vals2[SS];
    __shared__ float  wsa[4], wsb[4];

    const int tid   = threadIdx.x;
    const int bid   = blockIdx.x;
    const int batch = bid / KPB;
    const int k     = bid - batch * KPB;
    const bool pair = (k > 0) && (k < 256);
    int row_a;
    if (k == 0)        row_a = batch * TT;            // single: row 0
    else if (k == 256) row_a = batch * TT + 511;      // single: row 511
    else               row_a = batch * TT + 2 * k - 1; // pair (odd, even)
    const int row_b = pair ? row_a + 1 : row_a;

    // ---- prologue: metadata + zeroed vals ----
    for (int i = tid; i < NW + 1; i += 256) bmpre[i] = bmpre_g[batch * NWP + i];
    ((float4*)vals2)[tid]       = make_float4(0.f, 0.f, 0.f, 0.f);
    ((float4*)vals2)[tid + 256] = make_float4(0.f, 0.f, 0.f, 0.f);
    __syncthreads();

    // ---- pass 1: vals2 accumulate + p_gen dots (ranks shared per batch) ----
    const float4*  aA  = (const float4*)(attn + (size_t)row_a * SS);
    const float4*  aB  = (const float4*)(attn + (size_t)row_b * SS);
    const float4*  sp4 = (const float4*)(src_proj + batch * SS);
    const ushort4* r4p = (const ushort4*)(rank_g + batch * SS);
    const float4  va = aA[tid];
    const float4  p  = sp4[tid];
    const ushort4 r  = r4p[tid];
    atomicAdd(&vals2[r.x].x, va.x);
    atomicAdd(&vals2[r.y].x, va.y);
    atomicAdd(&vals2[r.z].x, va.z);
    atomicAdd(&vals2[r.w].x, va.w);
    float accA = va.x * p.x + va.y * p.y + va.z * p.z + va.w * p.w;
    float accB = 0.f;
    if (pair) {
        const float4 vb = aB[tid];
        atomicAdd(&vals2[r.x].y, vb.x);
        atomicAdd(&vals2[r.y].y, vb.y);
        atomicAdd(&vals2[r.z].y, vb.z);
        atomicAdd(&vals2[r.w].y, vb.w);
        accB = vb.x * p.x + vb.y * p.y + vb.z * p.z + vb.w * p.w;
    }
#pragma unroll
    for (int off = 32; off > 0; off >>= 1) {
        accA += __shfl_down(accA, off);
        accB += __shfl_down(accB, off);
    }
    if ((tid & 63) == 0) { wsa[tid >> 6] = accA; wsb[tid >> 6] = accB; }
    __syncthreads();   // vals2 final + wsa/wsb visible
    if (tid == 0) {
        const float x = wsa[0] + wsa[1] + wsa[2] + wsa[3] + tgt_proj[row_a];
        out[row_a] = 1.f / (1.f + expf(-x));
    }
    if (pair && tid == 1) {
        const float x = wsb[0] + wsb[1] + wsb[2] + wsb[3] + tgt_proj[row_b];
        out[row_b] = 1.f / (1.f + expf(-x));
    }

    // ---- sweep ----
    float* la = out + (BB * TT) + (size_t)row_a * VV;
    const int h = (4 - (row_a & 3)) & 3;       // row_a's aligned head (floats)
    const int n = (VV - h) >> 2;               // aligned float4 groups

    const int wv = tid >> 6;                   // wave id 0..3
    const int ln = tid & 63;                   // lane id
    const int nK = n >> 10;                    // full 1024-group outer iters

    if (pair) {
        float* lb = la + VV;                   // head_b = h - 1 (h >= 1: row_a odd)
        for (int kk = 0; kk < nK; ++kk) {
            const int base = (kk << 10) + (wv << 8) + ln;
#pragma unroll
            for (int q = 0; q < 4; ++q) PAIR_BODY(base + (q << 6));
        }
        for (int i = (nK << 10) + tid; i < n; i += 256) PAIR_BODY(i);
        // heads (<=3 and <=2 scalars) and tails (<=2 and <=3 scalars)
        if (tid < h)     la[tid] = lut2(tid, bmpre, vals2).x;
        if (tid < h - 1) lb[tid] = lut2(tid, bmpre, vals2).y;
        const int ta = h + (n << 2);
        if (ta + tid < VV) la[ta + tid] = lut2(ta + tid, bmpre, vals2).x;
        const int tb = (h - 1) + (n << 2);
        if (tb + tid < VV) lb[tb + tid] = lut2(tb + tid, bmpre, vals2).y;
    } else {
        for (int kk = 0; kk < nK; ++kk) {
            const int base = (kk << 10) + (wv << 8) + ln;
#pragma unroll
            for (int q = 0; q < 4; ++q) SINGLE_BODY(base + (q << 6));
        }
        for (int i = (nK << 10) + tid; i < n; i += 256) SINGLE_BODY(i);
        if (tid < h) la[tid] = lut2(tid, bmpre, vals2).x;
        const int ta = h + (n << 2);
        if (ta + tid < VV) la[ta + tid] = lut2(ta + tid, bmpre, vals2).x;
    }
}

extern "C" void kernel_launch(void* const* d_in, const int* in_sizes, int n_in,
                              void* d_out, int out_size, void* d_ws, size_t ws_size,
                              hipStream_t stream) {
    const int*   ids  = (const int*)d_in[0];    // [B,S]
    const float* attn = (const float*)d_in[1];  // [B,T,S]
    const float* src  = (const float*)d_in[2];  // [B,S,H]
    const float* tgt  = (const float*)d_in[3];  // [B,T,H]
    const float* W    = (const float*)d_in[4];  // [2H,1]
    const float* bp   = (const float*)d_in[5];  // [1]

    float* out = (float*)d_out;                 // [B*T (p_gen) | B*T*V]

    // ws layout (all 16B-aligned)
    float*          src_proj = (float*)d_ws;                          // 4096 f
    float*          tgt_proj = src_proj + BB * SS;                    // 2048 f
    uint2*          bmpre_g  = (uint2*)(tgt_proj + BB * TT);          // B*NWP uint2
    unsigned short* rank_g   = (unsigned short*)(bmpre_g + BB * NWP); // B*S u16

    prep_kernel<<<NPROJ + BB, 256, 0, stream>>>(
        src, tgt, W, bp, ids, src_proj, tgt_proj, bmpre_g, rank_g);
    row_kernel<<<BB * KPB, 256, 0, stream>>>(
        attn, src_proj, tgt_proj, bmpre_g, rank_g, out);
}